// Round 9
// baseline (1444.713 us; speedup 1.0000x reference)
//
#include <hip/hip_runtime.h>

#define T_ 96
#define N_ 1140
#define F_ 64
#define H_ 32
#define E_ 22800
#define LH_ 250
#define G4_ 1000
#define OUT_ 2280
#define KIN_ 36480   // N_*H_
#define SPLITK 60
#define KC 32
#define BN 32
#define NWG_LSTM 256

typedef _Float16 h2_t __attribute__((ext_vector_type(2)));
typedef unsigned long long u64;

__device__ __forceinline__ float leaky02(float x){ return x > 0.f ? x : 0.2f*x; }
__device__ __forceinline__ float fsigm(float x){ return 1.f/(1.f + __expf(-x)); }
__device__ __forceinline__ float ftanh(float x){
  x = fminf(fmaxf(x, -15.f), 15.f);
  float t = __expf(2.f * x);
  return (t - 1.f) / (t + 1.f);
}
__device__ __forceinline__ unsigned packh2(float a, float b) {
  auto p = __builtin_amdgcn_cvt_pkrtz(a, b);   // __fp16 ext_vector(2)
  return __builtin_bit_cast(unsigned, p);
}
__device__ __forceinline__ float fdot2u(unsigned w, unsigned h, float acc) {
  return __builtin_amdgcn_fdot2(__builtin_bit_cast(h2_t, w),
                                __builtin_bit_cast(h2_t, h), acc, false);
}

// mode==1 (XCD): L2-executing ops (no sc1). Polls are RMWs (always bypass L1;
// z is a runtime zero so the compiler cannot fold fetch_add->plain load).
// mode==2 (GLOBAL): agent-scope sc1 ops = R4-proven semantics.
__device__ __forceinline__ int poll_i(int* p, int mode, int z) {
  if (mode == 1) return __hip_atomic_fetch_add(p, z, __ATOMIC_RELAXED, __HIP_MEMORY_SCOPE_WORKGROUP);
  return __hip_atomic_load(p, __ATOMIC_RELAXED, __HIP_MEMORY_SCOPE_AGENT);
}
__device__ __forceinline__ u64 poll_u64(u64* p, int mode, u64 z) {
  if (mode == 1) return __hip_atomic_fetch_add(p, z, __ATOMIC_RELAXED, __HIP_MEMORY_SCOPE_WORKGROUP);
  return __hip_atomic_load(p, __ATOMIC_RELAXED, __HIP_MEMORY_SCOPE_AGENT);
}
__device__ __forceinline__ void post_u32(unsigned* p, unsigned v, int mode) {
  if (mode == 1) (void)__hip_atomic_exchange(p, v, __ATOMIC_RELAXED, __HIP_MEMORY_SCOPE_WORKGROUP);
  else __hip_atomic_store(p, v, __ATOMIC_RELAXED, __HIP_MEMORY_SCOPE_AGENT);
}
__device__ __forceinline__ void post_i(int* p, int v, int mode) {
  if (mode == 1) (void)__hip_atomic_exchange(p, v, __ATOMIC_RELAXED, __HIP_MEMORY_SCOPE_WORKGROUP);
  else __hip_atomic_store(p, v, __ATOMIC_RELAXED, __HIP_MEMORY_SCOPE_AGENT);
}

// ---------------- GAT feature transform: H = x@W, HS = H@a_s, HD = H@a_d ----
__global__ void k_feat(const float* __restrict__ x, const float* __restrict__ W,
                       const float* __restrict__ as_, const float* __restrict__ ad_,
                       float* __restrict__ Hout, float* __restrict__ HS,
                       float* __restrict__ HD, int K) {
  int gid = blockIdx.x * blockDim.x + threadIdx.x;
  int row = gid >> 5; int c = gid & 31;
  if (row >= T_ * N_) return;
  const float* xr = x + (size_t)row * K;
  float acc = 0.f;
  for (int k = 0; k < K; ++k) acc += xr[k] * W[k * H_ + c];
  Hout[(size_t)row * H_ + c] = acc;
  float ps = acc * as_[c], pd = acc * ad_[c];
  #pragma unroll
  for (int off = 16; off > 0; off >>= 1) {
    ps += __shfl_xor(ps, off, 32);
    pd += __shfl_xor(pd, off, 32);
  }
  if (c == 0) { HS[row] = ps; HD[row] = pd; }
}

// ---------------- CSR build ------------------------------------------------
__global__ void k_count(const int* __restrict__ ei, int* __restrict__ counts) {
  int gid = blockIdx.x * blockDim.x + threadIdx.x;
  if (gid >= T_ * E_) return;
  int t = gid / E_; int k = gid - t * E_;
  int dst = ei[(size_t)t * 2 * E_ + E_ + k];
  atomicAdd(&counts[t * N_ + dst], 1);
}

__global__ void k_scan(const int* __restrict__ counts, int* __restrict__ offs,
                       int* __restrict__ cursor) {
  int t = blockIdx.x; int tid = threadIdx.x;
  int base = tid * 5;
  int v[5]; int s = 0;
  #pragma unroll
  for (int r = 0; r < 5; ++r) {
    int i = base + r;
    int c = (i < N_) ? counts[t * N_ + i] : 0;
    v[r] = c; s += c;
  }
  __shared__ int sh[256];
  sh[tid] = s; __syncthreads();
  for (int off = 1; off < 256; off <<= 1) {
    int add = (tid >= off) ? sh[tid - off] : 0;
    __syncthreads();
    sh[tid] += add;
    __syncthreads();
  }
  int run = sh[tid] - s;  // exclusive prefix of this thread's chunk
  #pragma unroll
  for (int r = 0; r < 5; ++r) {
    int i = base + r;
    if (i < N_) { offs[t * (N_ + 1) + i] = run; cursor[t * N_ + i] = run; }
    run += v[r];
  }
  if (tid == 255) offs[t * (N_ + 1) + N_] = sh[255];
}

__global__ void k_fill(const int* __restrict__ ei, int* __restrict__ cursor,
                       int* __restrict__ elist) {
  int gid = blockIdx.x * blockDim.x + threadIdx.x;
  if (gid >= T_ * E_) return;
  int t = gid / E_; int k = gid - t * E_;
  int src = ei[(size_t)t * 2 * E_ + k];
  int dst = ei[(size_t)t * 2 * E_ + E_ + k];
  int pos = atomicAdd(&cursor[t * N_ + dst], 1);
  elist[(size_t)t * E_ + pos] = src;
}

// ---------------- GAT attention aggregate (online softmax per dst) ---------
__global__ void k_aggr(const float* __restrict__ Hf, const float* __restrict__ HS,
                       const float* __restrict__ HD, const int* __restrict__ offs,
                       const int* __restrict__ elist, const float* __restrict__ b,
                       float* __restrict__ Xout, int relu) {
  int gid = blockIdx.x * blockDim.x + threadIdx.x;
  int row = gid >> 5; int c = gid & 31;
  if (row >= T_ * N_) return;
  int t = row / N_; int i = row - t * N_;
  float hd_i = HD[row];
  float m = leaky02(HS[row] + hd_i);   // self-loop
  float s = 1.f;
  float acc = Hf[(size_t)row * H_ + c];
  int e0 = offs[t * (N_ + 1) + i], e1 = offs[t * (N_ + 1) + i + 1];
  const int* el = elist + (size_t)t * E_;
  const float* Ht = Hf + (size_t)t * N_ * H_;
  const float* HSt = HS + t * N_;
  float hsA = 0.f, hvA = 0.f;
  if (e0 < e1) {
    int srcA = el[e0];
    hsA = HSt[srcA];
    hvA = Ht[(size_t)srcA * H_ + c];
  }
  for (int e = e0; e < e1; ++e) {
    float hs = hsA, hv = hvA;
    if (e + 1 < e1) {
      int srcA = el[e + 1];
      hsA = HSt[srcA];
      hvA = Ht[(size_t)srcA * H_ + c];
    }
    float eg = leaky02(hs + hd_i);
    float mn = fmaxf(m, eg);
    float scl = __expf(m - mn);
    float p = __expf(eg - mn);
    s = s * scl + p;
    acc = acc * scl + p * hv;
    m = mn;
  }
  float val = acc / s + b[c];
  if (relu) val = fmaxf(val, 0.f);
  Xout[(size_t)row * H_ + c] = val;
}

// ------- LSTM0 input GEMM (f16 dot2): (96 x 36480) @ (36480 x 1000)^T ------
__global__ void k_gemm(const float* __restrict__ X, const float* __restrict__ Wih,
                       float* __restrict__ Gpart) {
  __shared__ unsigned Xs[T_][KC / 2 + 1];   // f16 pairs along K
  __shared__ unsigned Ws[BN][KC / 2 + 1];
  int j0 = blockIdx.x * BN;
  int sp = blockIdx.y;
  int tid = threadIdx.x;
  int jj = tid & 7;    // 8 j-groups of 4
  int tt = tid >> 3;   // 16 t-groups of 6
  float acc[6][4] = {};
  int kbeg = sp * (KIN_ / SPLITK);
  int kend = kbeg + (KIN_ / SPLITK);
  for (int k0 = kbeg; k0 < kend; k0 += KC) {
    for (int idx = tid; idx < T_ * (KC / 2); idx += 128) {
      int tr = idx >> 4; int kk = idx & 15;
      const float2 v = *(const float2*)(X + (size_t)tr * KIN_ + k0 + 2 * kk);
      Xs[tr][kk] = packh2(v.x, v.y);
    }
    for (int idx = tid; idx < BN * (KC / 2); idx += 128) {
      int jr = idx >> 4; int kk = idx & 15;
      int j = j0 + jr;
      unsigned v = 0;
      if (j < G4_) {
        const float2 w = *(const float2*)(Wih + (size_t)j * KIN_ + k0 + 2 * kk);
        v = packh2(w.x, w.y);
      }
      Ws[jr][kk] = v;
    }
    __syncthreads();
    for (int kk = 0; kk < KC / 2; ++kk) {
      unsigned xv[6], wv[4];
      #pragma unroll
      for (int r = 0; r < 6; ++r) xv[r] = Xs[tt * 6 + r][kk];
      #pragma unroll
      for (int q = 0; q < 4; ++q) wv[q] = Ws[jj * 4 + q][kk];
      #pragma unroll
      for (int r = 0; r < 6; ++r)
        #pragma unroll
        for (int q = 0; q < 4; ++q)
          acc[r][q] = fdot2u(wv[q], xv[r], acc[r][q]);
    }
    __syncthreads();
  }
  #pragma unroll
  for (int r = 0; r < 6; ++r) {
    int t = tt * 6 + r;
    #pragma unroll
    for (int q = 0; q < 4; ++q) {
      int j = j0 + jj * 4 + q;
      if (j < G4_) Gpart[((size_t)sp * T_ + t) * 1024 + j] = acc[r][q];
    }
  }
}

// G0 reduced with gate-interleaved layout: G0[t*1000 + j*4 + g]
__global__ void k_gred(const float* __restrict__ Gpart, const float* __restrict__ bih,
                       const float* __restrict__ bhh, float* __restrict__ G0) {
  int idx = blockIdx.x * blockDim.x + threadIdx.x;
  if (idx >= T_ * G4_) return;
  int t = idx / G4_; int jg = idx - t * G4_;
  int j = jg >> 2, g = jg & 3;
  int c = g * LH_ + j;                      // gate-major column in Gpart
  float s = bih[c] + bhh[c];
  for (int sp = 0; sp < SPLITK; ++sp) s += Gpart[((size_t)sp * T_ + t) * 1024 + c];
  G0[idx] = s;
}

// ---------------- same-XCD (with verified fallback) 2-layer LSTM -----------
// 256 WGs x 512 register; rank-0 WG decides: >=8 WGs on XCD0 -> XCD mode
// (workers = first 8 on XCD0; exchange via local-L2 atomics: swap posts +
// fetch_add(z) polls, z = runtime zero) else GLOBAL mode (first 8 WGs by
// global rank; agent-scope sc1 exchange = R4-proven). Per step: wave0 of
// each worker WG polls split flags (flag0 after L0 post, flag1 after L1)
// and RMW-gathers the 128 h-words into LDS; 8 compute waves read LDS.
// sync[]: [0..7] per-XCD count, [8] global count, [9] mode|4, [15] zero,
// [16..23] flags0, [24..31] flags1.
__global__ void __launch_bounds__(512, 2) k_lstm(
    const float* __restrict__ G0, const float* __restrict__ Whh0,
    const float* __restrict__ Wih1, const float* __restrict__ Whh1,
    const float* __restrict__ bih1, const float* __restrict__ bhh1,
    const float* __restrict__ h0in, const float* __restrict__ c0in,
    unsigned* __restrict__ hp,     // [2 slots][2 layers][128] f16-pairs
    int* __restrict__ sync,
    float* __restrict__ ylast) {
  __shared__ __align__(8) unsigned ldsX[128];
  __shared__ __align__(8) unsigned ldsH1[128];
  __shared__ int sh_role, sh_mode;

  int tid = threadIdx.x;
  // ---- election ----
  if (tid == 0) {
    int xcd;
    asm volatile("s_getreg_b32 %0, hwreg(HW_REG_XCC_ID)" : "=s"(xcd));
    xcd &= 7;
    int r = -1;
    if (xcd == 0)
      r = __hip_atomic_fetch_add(&sync[0], 1, __ATOMIC_RELAXED, __HIP_MEMORY_SCOPE_AGENT);
    int g = __hip_atomic_fetch_add(&sync[8], 1, __ATOMIC_RELAXED, __HIP_MEMORY_SCOPE_AGENT);
    if (g == 0) {
      int guard = 0;
      while (__hip_atomic_load(&sync[8], __ATOMIC_RELAXED, __HIP_MEMORY_SCOPE_AGENT) < NWG_LSTM
             && ++guard < (1 << 22)) __builtin_amdgcn_s_sleep(2);
      int c0 = __hip_atomic_load(&sync[0], __ATOMIC_RELAXED, __HIP_MEMORY_SCOPE_AGENT);
      int md = (c0 >= 8) ? 1 : 2;
      __hip_atomic_store(&sync[9], 4 | md, __ATOMIC_RELAXED, __HIP_MEMORY_SCOPE_AGENT);
    }
    int mv, guard = 0;
    for (;;) {
      mv = __hip_atomic_load(&sync[9], __ATOMIC_RELAXED, __HIP_MEMORY_SCOPE_AGENT);
      if (mv & 4) break;
      if (++guard > (1 << 22)) { mv = 4 | 2; break; }
      __builtin_amdgcn_s_sleep(2);
    }
    int mode = mv & 3;
    int role;
    if (mode == 1) role = (xcd == 0 && r >= 0 && r < 8) ? r : -1;
    else           role = (g < 8) ? g : -1;
    sh_role = role; sh_mode = mode;
  }
  __syncthreads();
  int role = sh_role, mode = sh_mode;
  if (role < 0) return;

  int* flags0 = sync + 16;
  int* flags1 = sync + 24;
  u64* hp64 = (u64*)hp;
  int z = sync[15];              // runtime zero (never written)
  u64 zu = (u64)(unsigned)z;

  int wave = tid >> 6;
  int lane = tid & 63;
  int wv = role * 8 + wave;      // 0..63
  int qg = lane >> 4;            // gate: 0=i 1=f 2=g 3=o
  int ql = lane & 15;

  unsigned w0[4][8], wx1[4][8], wh1[4][8];
  float bs1[4], c0l[4], c1l[4];
  bool act[4];
  #pragma unroll
  for (int u = 0; u < 4; ++u) {
    int U = wv * 4 + u;
    act[u] = (U < LH_);
    int Uc = act[u] ? U : 0;
    size_t rb = (size_t)(qg * LH_ + Uc) * LH_;
    #pragma unroll
    for (int m = 0; m < 8; ++m) {
      int pi = m * 16 + ql;
      if (act[u] && pi < 125) {
        w0[u][m]  = packh2(Whh0[rb + 2 * pi], Whh0[rb + 2 * pi + 1]);
        wx1[u][m] = packh2(Wih1[rb + 2 * pi], Wih1[rb + 2 * pi + 1]);
        wh1[u][m] = packh2(Whh1[rb + 2 * pi], Whh1[rb + 2 * pi + 1]);
      } else { w0[u][m] = 0; wx1[u][m] = 0; wh1[u][m] = 0; }
    }
    bs1[u] = act[u] ? (bih1[qg * LH_ + Uc] + bhh1[qg * LH_ + Uc]) : 0.f;
    c0l[u] = act[u] ? c0in[Uc] : 0.f;
    c1l[u] = act[u] ? c0in[LH_ + Uc] : 0.f;
  }

  float gpre[4];
  #pragma unroll
  for (int u = 0; u < 4; ++u)
    gpre[u] = act[u] ? G0[0 * G4_ + (wv * 4 + u) * 4 + qg] : 0.f;

  for (int p = 0; p <= T_; ++p) {
    unsigned x0p[8], h1p[8];
    if (p == 0) {
      #pragma unroll
      for (int m = 0; m < 8; ++m) {
        int pi = m * 16 + ql;
        x0p[m] = (pi < 125) ? packh2(h0in[2 * pi], h0in[2 * pi + 1]) : 0u;
        h1p[m] = 0u;
      }
    } else {
      if (wave == 0) {
        // poll flags: h0[p-1] posted (flag0>=p); h1[p-2] posted (flag1>=p-1)
        int i8 = lane & 7;
        int need1 = (p >= 2) ? (p - 1) : 0;
        int guard = 0;
        for (;;) {
          int f0 = poll_i(&flags0[i8], mode, z);
          int f1 = (p >= 2) ? poll_i(&flags1[i8], mode, z) : need1;
          if (__all(f0 >= p && f1 >= need1)) break;
          if (++guard > (1 << 22)) break;
          __builtin_amdgcn_s_sleep(1);
        }
        // gather h into LDS (RMW loads: L1-bypassing in XCD mode)
        u64 xv = poll_u64(&hp64[(size_t)((p - 1) & 1) * 128 + lane], mode, zu);
        ((u64*)ldsX)[lane] = xv;
        if (p >= 2) {
          u64 hv = poll_u64(&hp64[(size_t)(p & 1) * 128 + 64 + lane], mode, zu);
          ((u64*)ldsH1)[lane] = hv;
        }
      }
      __syncthreads();
      #pragma unroll
      for (int m = 0; m < 8; ++m) x0p[m] = ldsX[m * 16 + ql];
      if (p == 1) {
        #pragma unroll
        for (int m = 0; m < 8; ++m) {
          int pi = m * 16 + ql;
          h1p[m] = (pi < 125) ? packh2(h0in[LH_ + 2 * pi], h0in[LH_ + 2 * pi + 1]) : 0u;
        }
      } else {
        #pragma unroll
        for (int m = 0; m < 8; ++m) h1p[m] = ldsH1[m * 16 + ql];
      }
    }

    // ---- layer 0, step p ----
    if (p < T_) {
      float h0new[4];
      #pragma unroll
      for (int u = 0; u < 4; ++u) {
        float s = 0.f;
        #pragma unroll
        for (int m = 0; m < 8; ++m) s = fdot2u(w0[u][m], x0p[m], s);
        s += __shfl_xor(s, 1); s += __shfl_xor(s, 2);
        s += __shfl_xor(s, 4); s += __shfl_xor(s, 8);
        float pre = s + gpre[u];
        float a = (qg == 2) ? ftanh(pre) : fsigm(pre);
        float ai = __shfl(a, ql);
        float af = __shfl(a, 16 + ql);
        float ag = __shfl(a, 32 + ql);
        float ao = __shfl(a, 48 + ql);
        c0l[u] = af * c0l[u] + ai * ag;
        h0new[u] = act[u] ? (ao * ftanh(c0l[u])) : 0.f;
      }
      int w = 2 * wv + lane;
      if (lane < 2 && w < 125) {
        unsigned pair = (lane == 0) ? packh2(h0new[0], h0new[1])
                                    : packh2(h0new[2], h0new[3]);
        post_u32(&hp[(size_t)(p & 1) * 256 + w], pair, mode);
      }
    }
    // ---- layer 1, step p-1 ----
    if (p >= 1) {
      float h1new[4];
      #pragma unroll
      for (int u = 0; u < 4; ++u) {
        float s = 0.f;
        #pragma unroll
        for (int m = 0; m < 8; ++m) s = fdot2u(wx1[u][m], x0p[m], s);
        #pragma unroll
        for (int m = 0; m < 8; ++m) s = fdot2u(wh1[u][m], h1p[m], s);
        s += __shfl_xor(s, 1); s += __shfl_xor(s, 2);
        s += __shfl_xor(s, 4); s += __shfl_xor(s, 8);
        float pre = s + bs1[u];
        float a = (qg == 2) ? ftanh(pre) : fsigm(pre);
        float bi = __shfl(a, ql);
        float bf = __shfl(a, 16 + ql);
        float bg = __shfl(a, 32 + ql);
        float bo = __shfl(a, 48 + ql);
        c1l[u] = bf * c1l[u] + bi * bg;
        h1new[u] = act[u] ? (bo * ftanh(c1l[u])) : 0.f;
      }
      if (p - 1 == T_ - 1) {
        if (lane == 0) {
          #pragma unroll
          for (int u = 0; u < 4; ++u)
            if (act[u]) ylast[wv * 4 + u] = h1new[u];
        }
      } else {
        int w = 2 * wv + lane;
        if (lane < 2 && w < 125) {
          unsigned pair = (lane == 0) ? packh2(h1new[0], h1new[1])
                                      : packh2(h1new[2], h1new[3]);
          post_u32(&hp[(size_t)((p - 1) & 1) * 256 + 128 + w], pair, mode);
        }
      }
    }
    // ---- prefetch next step's G0 ----
    float gnext[4];
    #pragma unroll
    for (int u = 0; u < 4; ++u)
      gnext[u] = (p + 1 < T_ && act[u]) ? G0[(p + 1) * G4_ + (wv * 4 + u) * 4 + qg] : 0.f;
    // ---- publish flags (posts drained by pre-barrier vmcnt waits) ----
    if (p < T_) {
      __syncthreads();
      if (tid == 0) {
        asm volatile("s_waitcnt vmcnt(0)" ::: "memory");
        post_i(&flags0[role], p + 1, mode);
        if (p >= 1) post_i(&flags1[role], p, mode);
      }
    }
    #pragma unroll
    for (int u = 0; u < 4; ++u) gpre[u] = gnext[u];
  }
}

// ---------------- 4 FC heads ----------------------------------------------
__global__ void k_fc(const float* __restrict__ ylast,
                     const float* __restrict__ Wa, const float* __restrict__ ba,
                     const float* __restrict__ Wb, const float* __restrict__ bb,
                     const float* __restrict__ Wc, const float* __restrict__ bc,
                     const float* __restrict__ Wd, const float* __restrict__ bd,
                     float* __restrict__ out) {
  int wg = blockIdx.x * 4 + (threadIdx.x >> 6);
  int lane = threadIdx.x & 63;
  if (wg >= 4 * OUT_) return;
  int head = wg / OUT_, o = wg - head * OUT_;
  const float* W = head == 0 ? Wa : head == 1 ? Wb : head == 2 ? Wc : Wd;
  const float* b = head == 0 ? ba : head == 1 ? bb : head == 2 ? bc : bd;
  float s = 0.f;
  #pragma unroll
  for (int r = 0; r < 4; ++r) {
    int idx = r * 64 + lane;
    if (idx < LH_) s += ylast[idx] * W[(size_t)o * LH_ + idx];
  }
  #pragma unroll
  for (int off = 32; off > 0; off >>= 1) s += __shfl_xor(s, off, 64);
  if (lane == 0) out[wg] = s + b[o];
}

// ---------------- launch ---------------------------------------------------
extern "C" void kernel_launch(void* const* d_in, const int* in_sizes, int n_in,
                              void* d_out, int out_size, void* d_ws, size_t ws_size,
                              hipStream_t stream) {
  const float* nodes = (const float*)d_in[0];
  const int*   ei    = (const int*)d_in[1];
  const float* W1    = (const float*)d_in[3];
  const float* as1   = (const float*)d_in[4];
  const float* ad1   = (const float*)d_in[5];
  const float* b1    = (const float*)d_in[6];
  const float* W2    = (const float*)d_in[7];
  const float* as2   = (const float*)d_in[8];
  const float* ad2   = (const float*)d_in[9];
  const float* b2    = (const float*)d_in[10];
  const float* Wih0  = (const float*)d_in[11];
  const float* Whh0  = (const float*)d_in[12];
  const float* bih0  = (const float*)d_in[13];
  const float* bhh0  = (const float*)d_in[14];
  const float* Wih1  = (const float*)d_in[15];
  const float* Whh1  = (const float*)d_in[16];
  const float* bih1  = (const float*)d_in[17];
  const float* bhh1  = (const float*)d_in[18];
  const float* h0    = (const float*)d_in[19];
  const float* c0    = (const float*)d_in[20];
  const float* fW1   = (const float*)d_in[21];
  const float* fb1   = (const float*)d_in[22];
  const float* fW2   = (const float*)d_in[23];
  const float* fb2   = (const float*)d_in[24];
  const float* fW3   = (const float*)d_in[25];
  const float* fb3   = (const float*)d_in[26];
  const float* fW4   = (const float*)d_in[27];
  const float* fb4   = (const float*)d_in[28];
  float* out = (float*)d_out;

  // workspace layout (bytes). Gpart overlaps dead Hbuf/HS/HD/X1 region.
  const size_t o_Gpart  = 0;          // 60*96*1024*4 = 23,592,960
  const size_t o_H      = 0;
  const size_t o_HS     = 14008320;
  const size_t o_HD     = 14446080;
  const size_t o_X1     = 14883840;
  const size_t o_X2     = 28892160;
  const size_t o_counts = 42900480;
  const size_t o_offs   = 43338240;
  const size_t o_cursor = 43776512;
  const size_t o_elist  = 44214272;
  const size_t o_G0     = 52969472;   // 384,000
  const size_t o_hp     = 53353472;   // 2048
  const size_t o_sync   = 53355520;   // 256
  const size_t o_ylast  = 53355776;   // 1024
  const size_t total    = 53356800;
  if (ws_size < total) return;  // leaves d_out poisoned -> visible failure

  char* ws = (char*)d_ws;
  float*    Gpart  = (float*)(ws + o_Gpart);
  float*    Hbuf   = (float*)(ws + o_H);
  float*    HS     = (float*)(ws + o_HS);
  float*    HD     = (float*)(ws + o_HD);
  float*    X1     = (float*)(ws + o_X1);
  float*    X2     = (float*)(ws + o_X2);
  int*      counts = (int*)(ws + o_counts);
  int*      offs   = (int*)(ws + o_offs);
  int*      cursor = (int*)(ws + o_cursor);
  int*      elist  = (int*)(ws + o_elist);
  float*    G0     = (float*)(ws + o_G0);
  unsigned* hp     = (unsigned*)(ws + o_hp);
  int*      syncA  = (int*)(ws + o_sync);
  float*    ylast  = (float*)(ws + o_ylast);

  (void)hipMemsetAsync(counts, 0, (size_t)T_ * N_ * 4, stream);
  (void)hipMemsetAsync(hp, 0, 2048, stream);
  (void)hipMemsetAsync(syncA, 0, 256, stream);

  const int rows_grid = (T_ * N_ * H_) / 256;   // 13680
  const int eg = (T_ * E_ + 255) / 256;         // 8550

  // GAT layer 1
  k_feat<<<rows_grid, 256, 0, stream>>>(nodes, W1, as1, ad1, Hbuf, HS, HD, F_);
  k_count<<<eg, 256, 0, stream>>>(ei, counts);
  k_scan<<<T_, 256, 0, stream>>>(counts, offs, cursor);
  k_fill<<<eg, 256, 0, stream>>>(ei, cursor, elist);
  k_aggr<<<rows_grid, 256, 0, stream>>>(Hbuf, HS, HD, offs, elist, b1, X1, 1);
  // GAT layer 2
  k_feat<<<rows_grid, 256, 0, stream>>>(X1, W2, as2, ad2, Hbuf, HS, HD, H_);
  k_aggr<<<rows_grid, 256, 0, stream>>>(Hbuf, HS, HD, offs, elist, b2, X2, 0);
  // LSTM0 input projection (f16 dot2, SPLITK=60)
  k_gemm<<<dim3(32, SPLITK), 128, 0, stream>>>(X2, Wih0, Gpart);
  k_gred<<<(T_ * G4_ + 255) / 256, 256, 0, stream>>>(Gpart, bih0, bhh0, G0);
  // same-XCD (or fallback agent-scope) recurrence
  k_lstm<<<NWG_LSTM, 512, 0, stream>>>(G0, Whh0, Wih1, Whh1, bih1, bhh1, h0, c0,
                                       hp, syncA, ylast);
  // FC heads
  k_fc<<<OUT_, 256, 0, stream>>>(ylast, fW1, fb1, fW2, fb2, fW3, fb3, fW4, fb4, out);
}

// Round 10
// 1293.358 us; speedup vs baseline: 1.1170x; 1.1170x over previous
//
#include <hip/hip_runtime.h>

#define T_ 96
#define N_ 1140
#define F_ 64
#define H_ 32
#define E_ 22800
#define LH_ 250
#define G4_ 1000
#define OUT_ 2280
#define KIN_ 36480   // N_*H_
#define SPLITK 60
#define KC 32
#define BN 32

typedef _Float16 h2_t __attribute__((ext_vector_type(2)));
typedef unsigned long long u64;

__device__ __forceinline__ float leaky02(float x){ return x > 0.f ? x : 0.2f*x; }
__device__ __forceinline__ float fsigm(float x){ return 1.f/(1.f + __expf(-x)); }
__device__ __forceinline__ float ftanh(float x){
  x = fminf(fmaxf(x, -15.f), 15.f);
  float t = __expf(2.f * x);
  return (t - 1.f) / (t + 1.f);
}
__device__ __forceinline__ unsigned packh2(float a, float b) {
  auto p = __builtin_amdgcn_cvt_pkrtz(a, b);   // __fp16 ext_vector(2)
  return __builtin_bit_cast(unsigned, p);
}
__device__ __forceinline__ float fdot2u(unsigned w, unsigned h, float acc) {
  return __builtin_amdgcn_fdot2(__builtin_bit_cast(h2_t, w),
                                __builtin_bit_cast(h2_t, h), acc, false);
}
__device__ __forceinline__ float2 unpk(unsigned v) {
  h2_t h = __builtin_bit_cast(h2_t, v);
  return make_float2((float)h[0], (float)h[1]);
}
// write-once tagged streams: relaxed agent-scope (sc1) u64 atomics (R4-proven)
__device__ __forceinline__ void post64(u64* p, u64 v) {
  __hip_atomic_store(p, v, __ATOMIC_RELAXED, __HIP_MEMORY_SCOPE_AGENT);
}
__device__ __forceinline__ u64 ld64a(const u64* p) {
  return __hip_atomic_load((u64*)p, __ATOMIC_RELAXED, __HIP_MEMORY_SCOPE_AGENT);
}

// ---------------- GAT feature transform: H = x@W, HS = H@a_s, HD = H@a_d ----
__global__ void k_feat(const float* __restrict__ x, const float* __restrict__ W,
                       const float* __restrict__ as_, const float* __restrict__ ad_,
                       float* __restrict__ Hout, float* __restrict__ HS,
                       float* __restrict__ HD, int K) {
  int gid = blockIdx.x * blockDim.x + threadIdx.x;
  int row = gid >> 5; int c = gid & 31;
  if (row >= T_ * N_) return;
  const float* xr = x + (size_t)row * K;
  float acc = 0.f;
  for (int k = 0; k < K; ++k) acc += xr[k] * W[k * H_ + c];
  Hout[(size_t)row * H_ + c] = acc;
  float ps = acc * as_[c], pd = acc * ad_[c];
  #pragma unroll
  for (int off = 16; off > 0; off >>= 1) {
    ps += __shfl_xor(ps, off, 32);
    pd += __shfl_xor(pd, off, 32);
  }
  if (c == 0) { HS[row] = ps; HD[row] = pd; }
}

// ---------------- CSR build ------------------------------------------------
__global__ void k_count(const int* __restrict__ ei, int* __restrict__ counts) {
  int gid = blockIdx.x * blockDim.x + threadIdx.x;
  if (gid >= T_ * E_) return;
  int t = gid / E_; int k = gid - t * E_;
  int dst = ei[(size_t)t * 2 * E_ + E_ + k];
  atomicAdd(&counts[t * N_ + dst], 1);
}

__global__ void k_scan(const int* __restrict__ counts, int* __restrict__ offs,
                       int* __restrict__ cursor) {
  int t = blockIdx.x; int tid = threadIdx.x;
  int base = tid * 5;
  int v[5]; int s = 0;
  #pragma unroll
  for (int r = 0; r < 5; ++r) {
    int i = base + r;
    int c = (i < N_) ? counts[t * N_ + i] : 0;
    v[r] = c; s += c;
  }
  __shared__ int sh[256];
  sh[tid] = s; __syncthreads();
  for (int off = 1; off < 256; off <<= 1) {
    int add = (tid >= off) ? sh[tid - off] : 0;
    __syncthreads();
    sh[tid] += add;
    __syncthreads();
  }
  int run = sh[tid] - s;  // exclusive prefix of this thread's chunk
  #pragma unroll
  for (int r = 0; r < 5; ++r) {
    int i = base + r;
    if (i < N_) { offs[t * (N_ + 1) + i] = run; cursor[t * N_ + i] = run; }
    run += v[r];
  }
  if (tid == 255) offs[t * (N_ + 1) + N_] = sh[255];
}

__global__ void k_fill(const int* __restrict__ ei, int* __restrict__ cursor,
                       int* __restrict__ elist) {
  int gid = blockIdx.x * blockDim.x + threadIdx.x;
  if (gid >= T_ * E_) return;
  int t = gid / E_; int k = gid - t * E_;
  int src = ei[(size_t)t * 2 * E_ + k];
  int dst = ei[(size_t)t * 2 * E_ + E_ + k];
  int pos = atomicAdd(&cursor[t * N_ + dst], 1);
  elist[(size_t)t * E_ + pos] = src;
}

// ---------------- GAT attention aggregate (online softmax per dst) ---------
__global__ void k_aggr(const float* __restrict__ Hf, const float* __restrict__ HS,
                       const float* __restrict__ HD, const int* __restrict__ offs,
                       const int* __restrict__ elist, const float* __restrict__ b,
                       float* __restrict__ Xout, int relu) {
  int gid = blockIdx.x * blockDim.x + threadIdx.x;
  int row = gid >> 5; int c = gid & 31;
  if (row >= T_ * N_) return;
  int t = row / N_; int i = row - t * N_;
  float hd_i = HD[row];
  float m = leaky02(HS[row] + hd_i);   // self-loop
  float s = 1.f;
  float acc = Hf[(size_t)row * H_ + c];
  int e0 = offs[t * (N_ + 1) + i], e1 = offs[t * (N_ + 1) + i + 1];
  const int* el = elist + (size_t)t * E_;
  const float* Ht = Hf + (size_t)t * N_ * H_;
  const float* HSt = HS + t * N_;
  float hsA = 0.f, hvA = 0.f;
  if (e0 < e1) {
    int srcA = el[e0];
    hsA = HSt[srcA];
    hvA = Ht[(size_t)srcA * H_ + c];
  }
  for (int e = e0; e < e1; ++e) {
    float hs = hsA, hv = hvA;
    if (e + 1 < e1) {
      int srcA = el[e + 1];
      hsA = HSt[srcA];
      hvA = Ht[(size_t)srcA * H_ + c];
    }
    float eg = leaky02(hs + hd_i);
    float mn = fmaxf(m, eg);
    float scl = __expf(m - mn);
    float p = __expf(eg - mn);
    s = s * scl + p;
    acc = acc * scl + p * hv;
    m = mn;
  }
  float val = acc / s + b[c];
  if (relu) val = fmaxf(val, 0.f);
  Xout[(size_t)row * H_ + c] = val;
}

// ------- LSTM0 input GEMM (f16 dot2): (96 x 36480) @ (36480 x 1000)^T ------
__global__ void k_gemm(const float* __restrict__ X, const float* __restrict__ Wih,
                       float* __restrict__ Gpart) {
  __shared__ unsigned Xs[T_][KC / 2 + 1];   // f16 pairs along K
  __shared__ unsigned Ws[BN][KC / 2 + 1];
  int j0 = blockIdx.x * BN;
  int sp = blockIdx.y;
  int tid = threadIdx.x;
  int jj = tid & 7;    // 8 j-groups of 4
  int tt = tid >> 3;   // 16 t-groups of 6
  float acc[6][4] = {};
  int kbeg = sp * (KIN_ / SPLITK);
  int kend = kbeg + (KIN_ / SPLITK);
  for (int k0 = kbeg; k0 < kend; k0 += KC) {
    for (int idx = tid; idx < T_ * (KC / 2); idx += 128) {
      int tr = idx >> 4; int kk = idx & 15;
      const float2 v = *(const float2*)(X + (size_t)tr * KIN_ + k0 + 2 * kk);
      Xs[tr][kk] = packh2(v.x, v.y);
    }
    for (int idx = tid; idx < BN * (KC / 2); idx += 128) {
      int jr = idx >> 4; int kk = idx & 15;
      int j = j0 + jr;
      unsigned v = 0;
      if (j < G4_) {
        const float2 w = *(const float2*)(Wih + (size_t)j * KIN_ + k0 + 2 * kk);
        v = packh2(w.x, w.y);
      }
      Ws[jr][kk] = v;
    }
    __syncthreads();
    for (int kk = 0; kk < KC / 2; ++kk) {
      unsigned xv[6], wv[4];
      #pragma unroll
      for (int r = 0; r < 6; ++r) xv[r] = Xs[tt * 6 + r][kk];
      #pragma unroll
      for (int q = 0; q < 4; ++q) wv[q] = Ws[jj * 4 + q][kk];
      #pragma unroll
      for (int r = 0; r < 6; ++r)
        #pragma unroll
        for (int q = 0; q < 4; ++q)
          acc[r][q] = fdot2u(wv[q], xv[r], acc[r][q]);
    }
    __syncthreads();
  }
  #pragma unroll
  for (int r = 0; r < 6; ++r) {
    int t = tt * 6 + r;
    #pragma unroll
    for (int q = 0; q < 4; ++q) {
      int j = j0 + jj * 4 + q;
      if (j < G4_) Gpart[((size_t)sp * T_ + t) * 1024 + j] = acc[r][q];
    }
  }
}

// G0 reduced with gate-interleaved layout: G0[t*1000 + j*4 + g]
__global__ void k_gred(const float* __restrict__ Gpart, const float* __restrict__ bih,
                       const float* __restrict__ bhh, float* __restrict__ G0) {
  int idx = blockIdx.x * blockDim.x + threadIdx.x;
  if (idx >= T_ * G4_) return;
  int t = idx / G4_; int jg = idx - t * G4_;
  int j = jg >> 2, g = jg & 3;
  int c = g * LH_ + j;                      // gate-major column in Gpart
  float s = bih[c] + bhh[c];
  for (int sp = 0; sp < SPLITK; ++sp) s += Gpart[((size_t)sp * T_ + t) * 1024 + c];
  G0[idx] = s;
}

// ---------------- acyclic 3-stage pipelined 2-layer LSTM -------------------
// 3 WGs x 256 threads; role = blockIdx.x. Thread u owns unit u (4 gate rows
// x 250 inputs): rows i,f,g in VGPRs (384 u32 f16-pairs), row o in LDS
// (128 KiB, m-major -> consecutive-tid = consecutive banks, conflict-free).
// role0: full layer-0, h0 recurrence in LDS; posts h0[t] tagged stream.
// role1: partial[t] = Wih1 @ h0[t] (NO recurrence); consumes h0 stream,
//        posts partial stream (f16 pairs).
// role2: pre = partial + Whh1 @ h1[t-1] + b; h1 recurrence in LDS; ylast.
// Cross-WG edges are feed-forward only (producers run ahead; write-once
// buffers, no ring): latency = 2 pipeline fills, not 96 round trips.
__global__ void __launch_bounds__(256, 1) k_lstm3(
    const float* __restrict__ G0, const float* __restrict__ Whh0,
    const float* __restrict__ Wih1, const float* __restrict__ Whh1,
    const float* __restrict__ bih1, const float* __restrict__ bhh1,
    const float* __restrict__ h0in, const float* __restrict__ c0in,
    u64* __restrict__ hseq,        // [96][128] tagged {t+1, h0 f16-pair}
    u64* __restrict__ pseq,        // [96][512] tagged {t+1, partial f16-pair}
    float* __restrict__ ylast) {
  __shared__ __align__(16) unsigned ldsH[2][128];
  __shared__ unsigned ldsWO[128 * 256];    // 128 KiB: o-gate rows, m-major
  int tid = threadIdx.x;
  int role = blockIdx.x;
  int u = tid;
  bool act = (u < LH_);
  int lane = tid & 63;

  const float* Wm = (role == 0) ? Whh0 : (role == 1) ? Wih1 : Whh1;

  // ---- load weights (rows g*250+u): i,f,g -> VGPR; o -> LDS ----
  unsigned wA[128], wB[128], wC[128];
  {
    int uc = act ? u : 0;
    const float2* r0 = (const float2*)(Wm + (size_t)(0 * LH_ + uc) * LH_);
    const float2* r1 = (const float2*)(Wm + (size_t)(1 * LH_ + uc) * LH_);
    const float2* r2 = (const float2*)(Wm + (size_t)(2 * LH_ + uc) * LH_);
    const float2* r3 = (const float2*)(Wm + (size_t)(3 * LH_ + uc) * LH_);
    #pragma unroll
    for (int m = 0; m < 125; ++m) {
      float2 a = r0[m], b = r1[m], c = r2[m], d = r3[m];
      wA[m] = act ? packh2(a.x, a.y) : 0u;
      wB[m] = act ? packh2(b.x, b.y) : 0u;
      wC[m] = act ? packh2(c.x, c.y) : 0u;
      ldsWO[m * 256 + tid] = act ? packh2(d.x, d.y) : 0u;
    }
    #pragma unroll
    for (int m = 125; m < 128; ++m) {
      wA[m] = 0u; wB[m] = 0u; wC[m] = 0u;
      ldsWO[m * 256 + tid] = 0u;
    }
  }
  // ---- init h LDS buffers (tails stay zero forever) ----
  if (tid < 128) {
    unsigned v = 0;
    if (tid < 125) {
      if (role == 0) v = packh2(h0in[2 * tid], h0in[2 * tid + 1]);
      if (role == 2) v = packh2(h0in[LH_ + 2 * tid], h0in[LH_ + 2 * tid + 1]);
    }
    ldsH[0][tid] = v;
    ldsH[1][tid] = 0u;
  }
  float cst = 0.f, bsI = 0.f, bsF = 0.f, bsG = 0.f, bsO = 0.f;
  if (role == 0 && act) cst = c0in[u];
  if (role == 2 && act) {
    cst = c0in[LH_ + u];
    bsI = bih1[u] + bhh1[u];
    bsF = bih1[LH_ + u] + bhh1[LH_ + u];
    bsG = bih1[2 * LH_ + u] + bhh1[2 * LH_ + u];
    bsO = bih1[3 * LH_ + u] + bhh1[3 * LH_ + u];
  }
  __syncthreads();

  float4 gpre = make_float4(0.f, 0.f, 0.f, 0.f);
  if (role == 0 && act) gpre = *(const float4*)(G0 + 4 * u);

  for (int p = 0; p < T_; ++p) {
    int rb = p & 1, wb = (p + 1) & 1;
    // ---- role 1: poll h0[p] stream into ldsH[rb] ----
    if (role == 1) {
      if (tid < 125) {
        u64 v; int gg = 0;
        for (;;) {
          v = ld64a(&hseq[(size_t)p * 128 + tid]);
          if ((unsigned)(v >> 32) == (unsigned)(p + 1)) break;
          if (++gg > (1 << 15)) break;   // hang insurance only
        }
        ldsH[rb][tid] = (unsigned)v;
      }
      __syncthreads();
    }
    // ---- role 2: poll own partial words ----
    float pI = 0.f, pF = 0.f, pG = 0.f, pO = 0.f;
    if (role == 2 && act) {
      u64 v1, v2; int gg = 0;
      for (;;) {
        v1 = ld64a(&pseq[(size_t)p * 512 + 2 * u]);
        if ((unsigned)(v1 >> 32) == (unsigned)(p + 1)) break;
        if (++gg > (1 << 15)) break;
      }
      gg = 0;
      for (;;) {
        v2 = ld64a(&pseq[(size_t)p * 512 + 2 * u + 1]);
        if ((unsigned)(v2 >> 32) == (unsigned)(p + 1)) break;
        if (++gg > (1 << 15)) break;
      }
      float2 a = unpk((unsigned)v1), b = unpk((unsigned)v2);
      pI = a.x; pF = a.y; pG = b.x; pO = b.y;
    }
    // ---- dot products over ldsH[rb] (own-h or staged h0) ----
    float aI = 0.f, aF = 0.f, aG = 0.f, aO = 0.f;
    {
      const uint4* h4 = (const uint4*)ldsH[rb];
      #pragma unroll
      for (int mm = 0; mm < 32; ++mm) {
        uint4 hv = h4[mm];
        int m0 = 4 * mm;
        aI = fdot2u(wA[m0 + 0], hv.x, aI);
        aF = fdot2u(wB[m0 + 0], hv.x, aF);
        aG = fdot2u(wC[m0 + 0], hv.x, aG);
        aO = fdot2u(ldsWO[(m0 + 0) * 256 + tid], hv.x, aO);
        aI = fdot2u(wA[m0 + 1], hv.y, aI);
        aF = fdot2u(wB[m0 + 1], hv.y, aF);
        aG = fdot2u(wC[m0 + 1], hv.y, aG);
        aO = fdot2u(ldsWO[(m0 + 1) * 256 + tid], hv.y, aO);
        aI = fdot2u(wA[m0 + 2], hv.z, aI);
        aF = fdot2u(wB[m0 + 2], hv.z, aF);
        aG = fdot2u(wC[m0 + 2], hv.z, aG);
        aO = fdot2u(ldsWO[(m0 + 2) * 256 + tid], hv.z, aO);
        aI = fdot2u(wA[m0 + 3], hv.w, aI);
        aF = fdot2u(wB[m0 + 3], hv.w, aF);
        aG = fdot2u(wC[m0 + 3], hv.w, aG);
        aO = fdot2u(ldsWO[(m0 + 3) * 256 + tid], hv.w, aO);
      }
    }
    // ---- role-specific epilogue ----
    if (role == 0) {
      float preI = aI + gpre.x, preF = aF + gpre.y;
      float preG = aG + gpre.z, preO = aO + gpre.w;
      cst = fsigm(preF) * cst + fsigm(preI) * ftanh(preG);
      float h = fsigm(preO) * ftanh(cst);
      float hn = __shfl(h, lane + 1);
      if (act && !(tid & 1)) {
        unsigned pr = packh2(h, hn);
        ldsH[wb][tid >> 1] = pr;
        post64(&hseq[(size_t)p * 128 + (tid >> 1)],
               ((u64)(unsigned)(p + 1) << 32) | pr);
      }
      if (act && p + 1 < T_) gpre = *(const float4*)(G0 + (p + 1) * G4_ + 4 * u);
      __syncthreads();
    } else if (role == 1) {
      if (act) {
        post64(&pseq[(size_t)p * 512 + 2 * u],
               ((u64)(unsigned)(p + 1) << 32) | packh2(aI, aF));
        post64(&pseq[(size_t)p * 512 + 2 * u + 1],
               ((u64)(unsigned)(p + 1) << 32) | packh2(aG, aO));
      }
      // single sync per step (top of loop); double-buffered staging
    } else {
      float preI = aI + pI + bsI, preF = aF + pF + bsF;
      float preG = aG + pG + bsG, preO = aO + pO + bsO;
      cst = fsigm(preF) * cst + fsigm(preI) * ftanh(preG);
      float h = fsigm(preO) * ftanh(cst);
      if (p == T_ - 1) {
        if (act) ylast[u] = h;
      } else {
        float hn = __shfl(h, lane + 1);
        if (act && !(tid & 1)) ldsH[wb][tid >> 1] = packh2(h, hn);
      }
      __syncthreads();
    }
  }
}

// ---------------- 4 FC heads ----------------------------------------------
__global__ void k_fc(const float* __restrict__ ylast,
                     const float* __restrict__ Wa, const float* __restrict__ ba,
                     const float* __restrict__ Wb, const float* __restrict__ bb,
                     const float* __restrict__ Wc, const float* __restrict__ bc,
                     const float* __restrict__ Wd, const float* __restrict__ bd,
                     float* __restrict__ out) {
  int wg = blockIdx.x * 4 + (threadIdx.x >> 6);
  int lane = threadIdx.x & 63;
  if (wg >= 4 * OUT_) return;
  int head = wg / OUT_, o = wg - head * OUT_;
  const float* W = head == 0 ? Wa : head == 1 ? Wb : head == 2 ? Wc : Wd;
  const float* b = head == 0 ? ba : head == 1 ? bb : head == 2 ? bc : bd;
  float s = 0.f;
  #pragma unroll
  for (int r = 0; r < 4; ++r) {
    int idx = r * 64 + lane;
    if (idx < LH_) s += ylast[idx] * W[(size_t)o * LH_ + idx];
  }
  #pragma unroll
  for (int off = 32; off > 0; off >>= 1) s += __shfl_xor(s, off, 64);
  if (lane == 0) out[wg] = s + b[o];
}

// ---------------- launch ---------------------------------------------------
extern "C" void kernel_launch(void* const* d_in, const int* in_sizes, int n_in,
                              void* d_out, int out_size, void* d_ws, size_t ws_size,
                              hipStream_t stream) {
  const float* nodes = (const float*)d_in[0];
  const int*   ei    = (const int*)d_in[1];
  const float* W1    = (const float*)d_in[3];
  const float* as1   = (const float*)d_in[4];
  const float* ad1   = (const float*)d_in[5];
  const float* b1    = (const float*)d_in[6];
  const float* W2    = (const float*)d_in[7];
  const float* as2   = (const float*)d_in[8];
  const float* ad2   = (const float*)d_in[9];
  const float* b2    = (const float*)d_in[10];
  const float* Wih0  = (const float*)d_in[11];
  const float* Whh0  = (const float*)d_in[12];
  const float* bih0  = (const float*)d_in[13];
  const float* bhh0  = (const float*)d_in[14];
  const float* Wih1  = (const float*)d_in[15];
  const float* Whh1  = (const float*)d_in[16];
  const float* bih1  = (const float*)d_in[17];
  const float* bhh1  = (const float*)d_in[18];
  const float* h0    = (const float*)d_in[19];
  const float* c0    = (const float*)d_in[20];
  const float* fW1   = (const float*)d_in[21];
  const float* fb1   = (const float*)d_in[22];
  const float* fW2   = (const float*)d_in[23];
  const float* fb2   = (const float*)d_in[24];
  const float* fW3   = (const float*)d_in[25];
  const float* fb3   = (const float*)d_in[26];
  const float* fW4   = (const float*)d_in[27];
  const float* fb4   = (const float*)d_in[28];
  float* out = (float*)d_out;

  // workspace layout (bytes). Gpart overlaps dead Hbuf/HS/HD/X1 region.
  const size_t o_Gpart  = 0;          // 60*96*1024*4 = 23,592,960
  const size_t o_H      = 0;
  const size_t o_HS     = 14008320;
  const size_t o_HD     = 14446080;
  const size_t o_X1     = 14883840;
  const size_t o_X2     = 28892160;
  const size_t o_counts = 42900480;
  const size_t o_offs   = 43338240;
  const size_t o_cursor = 43776512;
  const size_t o_elist  = 44214272;
  const size_t o_G0     = 52969472;   // 384,000
  const size_t o_ylast  = 53353472;   // 1,024
  const size_t o_hseq   = 53354496;   // 96*128*8 = 98,304
  const size_t o_pseq   = 53452800;   // 96*512*8 = 393,216
  const size_t total    = 53846016;
  if (ws_size < total) return;  // leaves d_out poisoned -> visible failure

  char* ws = (char*)d_ws;
  float* Gpart  = (float*)(ws + o_Gpart);
  float* Hbuf   = (float*)(ws + o_H);
  float* HS     = (float*)(ws + o_HS);
  float* HD     = (float*)(ws + o_HD);
  float* X1     = (float*)(ws + o_X1);
  float* X2     = (float*)(ws + o_X2);
  int*   counts = (int*)(ws + o_counts);
  int*   offs   = (int*)(ws + o_offs);
  int*   cursor = (int*)(ws + o_cursor);
  int*   elist  = (int*)(ws + o_elist);
  float* G0     = (float*)(ws + o_G0);
  float* ylast  = (float*)(ws + o_ylast);
  u64*   hseq   = (u64*)(ws + o_hseq);
  u64*   pseq   = (u64*)(ws + o_pseq);

  (void)hipMemsetAsync(counts, 0, (size_t)T_ * N_ * 4, stream);
  (void)hipMemsetAsync(hseq, 0, 98304 + 393216, stream);  // hseq+pseq contiguous

  const int rows_grid = (T_ * N_ * H_) / 256;   // 13680
  const int eg = (T_ * E_ + 255) / 256;         // 8550

  // GAT layer 1
  k_feat<<<rows_grid, 256, 0, stream>>>(nodes, W1, as1, ad1, Hbuf, HS, HD, F_);
  k_count<<<eg, 256, 0, stream>>>(ei, counts);
  k_scan<<<T_, 256, 0, stream>>>(counts, offs, cursor);
  k_fill<<<eg, 256, 0, stream>>>(ei, cursor, elist);
  k_aggr<<<rows_grid, 256, 0, stream>>>(Hbuf, HS, HD, offs, elist, b1, X1, 1);
  // GAT layer 2
  k_feat<<<rows_grid, 256, 0, stream>>>(X1, W2, as2, ad2, Hbuf, HS, HD, H_);
  k_aggr<<<rows_grid, 256, 0, stream>>>(Hbuf, HS, HD, offs, elist, b2, X2, 0);
  // LSTM0 input projection (f16 dot2, SPLITK=60)
  k_gemm<<<dim3(32, SPLITK), 128, 0, stream>>>(X2, Wih0, Gpart);
  k_gred<<<(T_ * G4_ + 255) / 256, 256, 0, stream>>>(Gpart, bih0, bhh0, G0);
  // acyclic 3-stage pipelined recurrence
  k_lstm3<<<3, 256, 0, stream>>>(G0, Whh0, Wih1, Whh1, bih1, bhh1, h0, c0,
                                 hseq, pseq, ylast);
  // FC heads
  k_fc<<<OUT_, 256, 0, stream>>>(ylast, fW1, fb1, fW2, fb2, fW3, fb3, fW4, fb4, out);
}